// Round 1
// baseline (188.498 us; speedup 1.0000x reference)
//
#include <hip/hip_runtime.h>

constexpr int NN = 20000;
constexpr int FF = 256;

// Accumulate one combo: y[k] += mix * sum_{i,j} cg[i,j,k] * p[i*D2+j]
// cg layout: (D1, D2, DO) row-major; indices are compile-time constants so the
// address is wave-uniform -> backend scalarizes to s_load, FMA gets SGPR operand.
template<int D1, int D2, int DO>
__device__ __forceinline__ void accum_combo(const float* __restrict__ cg,
                                            float mix,
                                            const float* p,
                                            float* y) {
#pragma unroll
    for (int k = 0; k < DO; ++k) {
        float t = 0.0f;
#pragma unroll
        for (int i = 0; i < D1; ++i) {
#pragma unroll
            for (int j = 0; j < D2; ++j) {
                t = fmaf(cg[(i * D2 + j) * DO + k], p[i * D2 + j], t);
            }
        }
        y[k] = fmaf(mix, t, y[k]);
    }
}

__global__ __launch_bounds__(256) void selfmix_kernel(
    const float* __restrict__ x0, const float* __restrict__ x1,
    const float* __restrict__ x2, const float* __restrict__ x3,
    const float* __restrict__ keep0, const float* __restrict__ keep1,
    const float* __restrict__ keep2, const float* __restrict__ keep3,
    const float* __restrict__ mix011, const float* __restrict__ cg011,
    const float* __restrict__ mix022, const float* __restrict__ cg022,
    const float* __restrict__ mix033, const float* __restrict__ cg033,
    const float* __restrict__ mix121, const float* __restrict__ cg121,
    const float* __restrict__ mix122, const float* __restrict__ cg122,
    const float* __restrict__ mix123, const float* __restrict__ cg123,
    const float* __restrict__ mix132, const float* __restrict__ cg132,
    const float* __restrict__ mix133, const float* __restrict__ cg133,
    const float* __restrict__ mix231, const float* __restrict__ cg231,
    const float* __restrict__ mix232, const float* __restrict__ cg232,
    const float* __restrict__ mix233, const float* __restrict__ cg233,
    float* __restrict__ out)
{
    const int n = blockIdx.x;
    const int f = threadIdx.x;

    // ---- load x fragments (coalesced: lane = f, rows stride F) ----
    float a0;
    float a1[3], a2[5], a3[7];
    a0 = x0[n * FF + f];
#pragma unroll
    for (int i = 0; i < 3; ++i) a1[i] = x1[(n * 3 + i) * FF + f];
#pragma unroll
    for (int i = 0; i < 5; ++i) a2[i] = x2[(n * 5 + i) * FF + f];
#pragma unroll
    for (int i = 0; i < 7; ++i) a3[i] = x3[(n * 7 + i) * FF + f];

    // ---- keep path ----
    float y0;
    float y1[3], y2[5], y3[7];
    y0 = keep0[f] * a0;
    {
        const float k1 = keep1[f];
#pragma unroll
        for (int i = 0; i < 3; ++i) y1[i] = k1 * a1[i];
    }
    {
        const float k2 = keep2[f];
#pragma unroll
        for (int i = 0; i < 5; ++i) y2[i] = k2 * a2[i];
    }
    {
        const float k3 = keep3[f];
#pragma unroll
        for (int i = 0; i < 7; ++i) y3[i] = k3 * a3[i];
    }

    // ---- mixing path: shared pair products per (l1,l2) group ----
    // group (0,1): products p[j] = a0*a1[j]; feeds L=1
    {
        float p[3];
#pragma unroll
        for (int j = 0; j < 3; ++j) p[j] = a0 * a1[j];
        accum_combo<1, 3, 3>(cg011, mix011[f], p, y1);
    }
    // group (0,2): feeds L=2
    {
        float p[5];
#pragma unroll
        for (int j = 0; j < 5; ++j) p[j] = a0 * a2[j];
        accum_combo<1, 5, 5>(cg022, mix022[f], p, y2);
    }
    // group (0,3): feeds L=3
    {
        float p[7];
#pragma unroll
        for (int j = 0; j < 7; ++j) p[j] = a0 * a3[j];
        accum_combo<1, 7, 7>(cg033, mix033[f], p, y3);
    }
    // group (1,2): 15 products, feeds L=1,2,3
    {
        float p[15];
#pragma unroll
        for (int i = 0; i < 3; ++i)
#pragma unroll
            for (int j = 0; j < 5; ++j) p[i * 5 + j] = a1[i] * a2[j];
        accum_combo<3, 5, 3>(cg121, mix121[f], p, y1);
        accum_combo<3, 5, 5>(cg122, mix122[f], p, y2);
        accum_combo<3, 5, 7>(cg123, mix123[f], p, y3);
    }
    // group (1,3): 21 products, feeds L=2,3
    {
        float p[21];
#pragma unroll
        for (int i = 0; i < 3; ++i)
#pragma unroll
            for (int j = 0; j < 7; ++j) p[i * 7 + j] = a1[i] * a3[j];
        accum_combo<3, 7, 5>(cg132, mix132[f], p, y2);
        accum_combo<3, 7, 7>(cg133, mix133[f], p, y3);
    }
    // group (2,3): 35 products, feeds L=1,2,3
    {
        float p[35];
#pragma unroll
        for (int i = 0; i < 5; ++i)
#pragma unroll
            for (int j = 0; j < 7; ++j) p[i * 7 + j] = a2[i] * a3[j];
        accum_combo<5, 7, 3>(cg231, mix231[f], p, y1);
        accum_combo<5, 7, 5>(cg232, mix232[f], p, y2);
        accum_combo<5, 7, 7>(cg233, mix233[f], p, y3);
    }

    // ---- store (concatenated outputs: y0 | y1 | y2 | y3) ----
    float* __restrict__ o0 = out;                    // N*1*F
    float* __restrict__ o1 = out + (size_t)NN * FF;  // N*3*F
    float* __restrict__ o2 = out + (size_t)NN * 4 * FF;
    float* __restrict__ o3 = out + (size_t)NN * 9 * FF;

    o0[n * FF + f] = y0;
#pragma unroll
    for (int k = 0; k < 3; ++k) o1[(n * 3 + k) * FF + f] = y1[k];
#pragma unroll
    for (int k = 0; k < 5; ++k) o2[(n * 5 + k) * FF + f] = y2[k];
#pragma unroll
    for (int k = 0; k < 7; ++k) o3[(n * 7 + k) * FF + f] = y3[k];
}

extern "C" void kernel_launch(void* const* d_in, const int* in_sizes, int n_in,
                              void* d_out, int out_size, void* d_ws, size_t ws_size,
                              hipStream_t stream) {
    const float* x0 = (const float*)d_in[0];
    const float* x1 = (const float*)d_in[1];
    const float* x2 = (const float*)d_in[2];
    const float* x3 = (const float*)d_in[3];
    const float* keep0 = (const float*)d_in[4];
    const float* keep1 = (const float*)d_in[5];
    const float* keep2 = (const float*)d_in[6];
    const float* keep3 = (const float*)d_in[7];
    const float* mix011 = (const float*)d_in[8];
    const float* cg011  = (const float*)d_in[9];
    const float* mix022 = (const float*)d_in[10];
    const float* cg022  = (const float*)d_in[11];
    const float* mix033 = (const float*)d_in[12];
    const float* cg033  = (const float*)d_in[13];
    const float* mix121 = (const float*)d_in[14];
    const float* cg121  = (const float*)d_in[15];
    const float* mix122 = (const float*)d_in[16];
    const float* cg122  = (const float*)d_in[17];
    const float* mix123 = (const float*)d_in[18];
    const float* cg123  = (const float*)d_in[19];
    const float* mix132 = (const float*)d_in[20];
    const float* cg132  = (const float*)d_in[21];
    const float* mix133 = (const float*)d_in[22];
    const float* cg133  = (const float*)d_in[23];
    const float* mix231 = (const float*)d_in[24];
    const float* cg231  = (const float*)d_in[25];
    const float* mix232 = (const float*)d_in[26];
    const float* cg232  = (const float*)d_in[27];
    const float* mix233 = (const float*)d_in[28];
    const float* cg233  = (const float*)d_in[29];

    dim3 grid(NN);
    dim3 block(FF);
    hipLaunchKernelGGL(selfmix_kernel, grid, block, 0, stream,
                       x0, x1, x2, x3,
                       keep0, keep1, keep2, keep3,
                       mix011, cg011, mix022, cg022, mix033, cg033,
                       mix121, cg121, mix122, cg122, mix123, cg123,
                       mix132, cg132, mix133, cg133,
                       mix231, cg231, mix232, cg232, mix233, cg233,
                       (float*)d_out);
}

// Round 2
// 181.653 us; speedup vs baseline: 1.0377x; 1.0377x over previous
//
#include <hip/hip_runtime.h>
#include <stdint.h>

constexpr int NN = 20000;
constexpr int FF = 256;

// Force CG coefficient loads onto the scalar path: addrspace(4) (constant)
// + wave-uniform address -> s_load -> SGPR src operand in v_fma_f32.
typedef const __attribute__((address_space(4))) float* cgp;
#define CGP(p) ((cgp)(uintptr_t)(p))

__global__ __launch_bounds__(256, 2) void selfmix_kernel(
    const float* __restrict__ x0, const float* __restrict__ x1,
    const float* __restrict__ x2, const float* __restrict__ x3,
    const float* __restrict__ keep0, const float* __restrict__ keep1,
    const float* __restrict__ keep2, const float* __restrict__ keep3,
    const float* __restrict__ mix011, const float* __restrict__ cg011,
    const float* __restrict__ mix022, const float* __restrict__ cg022,
    const float* __restrict__ mix033, const float* __restrict__ cg033,
    const float* __restrict__ mix121, const float* __restrict__ cg121,
    const float* __restrict__ mix122, const float* __restrict__ cg122,
    const float* __restrict__ mix123, const float* __restrict__ cg123,
    const float* __restrict__ mix132, const float* __restrict__ cg132,
    const float* __restrict__ mix133, const float* __restrict__ cg133,
    const float* __restrict__ mix231, const float* __restrict__ cg231,
    const float* __restrict__ mix232, const float* __restrict__ cg232,
    const float* __restrict__ mix233, const float* __restrict__ cg233,
    float* __restrict__ out)
{
    const int n = blockIdx.x;
    const int f = threadIdx.x;

    // ---- load x fragments (coalesced; row offsets fold into imm offsets) ----
    float a0 = x0[n * FF + f];
    float a1[3], a2[5], a3[7];
    {
        const float* p1 = x1 + (n * 3) * FF + f;
#pragma unroll
        for (int i = 0; i < 3; ++i) a1[i] = p1[i * FF];
        const float* p2 = x2 + (n * 5) * FF + f;
#pragma unroll
        for (int i = 0; i < 5; ++i) a2[i] = p2[i * FF];
        const float* p3 = x3 + (n * 7) * FF + f;
#pragma unroll
        for (int i = 0; i < 7; ++i) a3[i] = p3[i * FF];
    }

    // ---- keep path ----
    float y0 = keep0[f] * a0;
    float y1[3], y2[5], y3[7];
    {
        const float k1 = keep1[f];
#pragma unroll
        for (int i = 0; i < 3; ++i) y1[i] = k1 * a1[i];
        const float k2 = keep2[f];
#pragma unroll
        for (int i = 0; i < 5; ++i) y2[i] = k2 * a2[i];
        const float k3 = keep3[f];
#pragma unroll
        for (int i = 0; i < 7; ++i) y3[i] = k3 * a3[i];
    }

    // ---- mixing path: ij-outer, k-inner; products are single live scalars ----

    // group (0,1) -> L=1
    {
        const float m = mix011[f];
        cgp cg = CGP(cg011);
        float t[3] = {0.f, 0.f, 0.f};
#pragma unroll
        for (int j = 0; j < 3; ++j) {
            const float p = a0 * a1[j];
#pragma unroll
            for (int k = 0; k < 3; ++k) t[k] = fmaf(cg[j * 3 + k], p, t[k]);
        }
#pragma unroll
        for (int k = 0; k < 3; ++k) y1[k] = fmaf(m, t[k], y1[k]);
    }

    // group (0,2) -> L=2
    {
        const float m = mix022[f];
        cgp cg = CGP(cg022);
        float t[5] = {0.f, 0.f, 0.f, 0.f, 0.f};
#pragma unroll
        for (int j = 0; j < 5; ++j) {
            const float p = a0 * a2[j];
#pragma unroll
            for (int k = 0; k < 5; ++k) t[k] = fmaf(cg[j * 5 + k], p, t[k]);
        }
#pragma unroll
        for (int k = 0; k < 5; ++k) y2[k] = fmaf(m, t[k], y2[k]);
    }

    // group (0,3) -> L=3
    {
        const float m = mix033[f];
        cgp cg = CGP(cg033);
        float t[7] = {0.f, 0.f, 0.f, 0.f, 0.f, 0.f, 0.f};
#pragma unroll
        for (int j = 0; j < 7; ++j) {
            const float p = a0 * a3[j];
#pragma unroll
            for (int k = 0; k < 7; ++k) t[k] = fmaf(cg[j * 7 + k], p, t[k]);
        }
#pragma unroll
        for (int k = 0; k < 7; ++k) y3[k] = fmaf(m, t[k], y3[k]);
    }

    // group (1,2) -> L=1,2,3 (shared products)
    {
        const float m1 = mix121[f], m2 = mix122[f], m3 = mix123[f];
        cgp c1 = CGP(cg121);
        cgp c2 = CGP(cg122);
        cgp c3 = CGP(cg123);
        float t1[3] = {0.f, 0.f, 0.f};
        float t2[5] = {0.f, 0.f, 0.f, 0.f, 0.f};
        float t3[7] = {0.f, 0.f, 0.f, 0.f, 0.f, 0.f, 0.f};
#pragma unroll
        for (int i = 0; i < 3; ++i) {
#pragma unroll
            for (int j = 0; j < 5; ++j) {
                const int ij = i * 5 + j;
                const float p = a1[i] * a2[j];
#pragma unroll
                for (int k = 0; k < 3; ++k) t1[k] = fmaf(c1[ij * 3 + k], p, t1[k]);
#pragma unroll
                for (int k = 0; k < 5; ++k) t2[k] = fmaf(c2[ij * 5 + k], p, t2[k]);
#pragma unroll
                for (int k = 0; k < 7; ++k) t3[k] = fmaf(c3[ij * 7 + k], p, t3[k]);
            }
        }
#pragma unroll
        for (int k = 0; k < 3; ++k) y1[k] = fmaf(m1, t1[k], y1[k]);
#pragma unroll
        for (int k = 0; k < 5; ++k) y2[k] = fmaf(m2, t2[k], y2[k]);
#pragma unroll
        for (int k = 0; k < 7; ++k) y3[k] = fmaf(m3, t3[k], y3[k]);
    }

    // group (1,3) -> L=2,3 (shared products)
    {
        const float m2 = mix132[f], m3 = mix133[f];
        cgp c2 = CGP(cg132);
        cgp c3 = CGP(cg133);
        float t2[5] = {0.f, 0.f, 0.f, 0.f, 0.f};
        float t3[7] = {0.f, 0.f, 0.f, 0.f, 0.f, 0.f, 0.f};
#pragma unroll
        for (int i = 0; i < 3; ++i) {
#pragma unroll
            for (int j = 0; j < 7; ++j) {
                const int ij = i * 7 + j;
                const float p = a1[i] * a3[j];
#pragma unroll
                for (int k = 0; k < 5; ++k) t2[k] = fmaf(c2[ij * 5 + k], p, t2[k]);
#pragma unroll
                for (int k = 0; k < 7; ++k) t3[k] = fmaf(c3[ij * 7 + k], p, t3[k]);
            }
        }
#pragma unroll
        for (int k = 0; k < 5; ++k) y2[k] = fmaf(m2, t2[k], y2[k]);
#pragma unroll
        for (int k = 0; k < 7; ++k) y3[k] = fmaf(m3, t3[k], y3[k]);
    }

    // group (2,3) -> L=1,2,3 (shared products)
    {
        const float m1 = mix231[f], m2 = mix232[f], m3 = mix233[f];
        cgp c1 = CGP(cg231);
        cgp c2 = CGP(cg232);
        cgp c3 = CGP(cg233);
        float t1[3] = {0.f, 0.f, 0.f};
        float t2[5] = {0.f, 0.f, 0.f, 0.f, 0.f};
        float t3[7] = {0.f, 0.f, 0.f, 0.f, 0.f, 0.f, 0.f};
#pragma unroll
        for (int i = 0; i < 5; ++i) {
#pragma unroll
            for (int j = 0; j < 7; ++j) {
                const int ij = i * 7 + j;
                const float p = a2[i] * a3[j];
#pragma unroll
                for (int k = 0; k < 3; ++k) t1[k] = fmaf(c1[ij * 3 + k], p, t1[k]);
#pragma unroll
                for (int k = 0; k < 5; ++k) t2[k] = fmaf(c2[ij * 5 + k], p, t2[k]);
#pragma unroll
                for (int k = 0; k < 7; ++k) t3[k] = fmaf(c3[ij * 7 + k], p, t3[k]);
            }
        }
#pragma unroll
        for (int k = 0; k < 3; ++k) y1[k] = fmaf(m1, t1[k], y1[k]);
#pragma unroll
        for (int k = 0; k < 5; ++k) y2[k] = fmaf(m2, t2[k], y2[k]);
#pragma unroll
        for (int k = 0; k < 7; ++k) y3[k] = fmaf(m3, t3[k], y3[k]);
    }

    // ---- store (concatenated outputs: y0 | y1 | y2 | y3) ----
    float* o0 = out;                          // N*1*F
    float* o1 = out + (size_t)NN * FF;        // N*3*F
    float* o2 = out + (size_t)NN * 4 * FF;    // N*5*F
    float* o3 = out + (size_t)NN * 9 * FF;    // N*7*F

    o0[n * FF + f] = y0;
    {
        float* q1 = o1 + (n * 3) * FF + f;
#pragma unroll
        for (int k = 0; k < 3; ++k) q1[k * FF] = y1[k];
        float* q2 = o2 + (n * 5) * FF + f;
#pragma unroll
        for (int k = 0; k < 5; ++k) q2[k * FF] = y2[k];
        float* q3 = o3 + (n * 7) * FF + f;
#pragma unroll
        for (int k = 0; k < 7; ++k) q3[k * FF] = y3[k];
    }
}

extern "C" void kernel_launch(void* const* d_in, const int* in_sizes, int n_in,
                              void* d_out, int out_size, void* d_ws, size_t ws_size,
                              hipStream_t stream) {
    const float* x0 = (const float*)d_in[0];
    const float* x1 = (const float*)d_in[1];
    const float* x2 = (const float*)d_in[2];
    const float* x3 = (const float*)d_in[3];
    const float* keep0 = (const float*)d_in[4];
    const float* keep1 = (const float*)d_in[5];
    const float* keep2 = (const float*)d_in[6];
    const float* keep3 = (const float*)d_in[7];
    const float* mix011 = (const float*)d_in[8];
    const float* cg011  = (const float*)d_in[9];
    const float* mix022 = (const float*)d_in[10];
    const float* cg022  = (const float*)d_in[11];
    const float* mix033 = (const float*)d_in[12];
    const float* cg033  = (const float*)d_in[13];
    const float* mix121 = (const float*)d_in[14];
    const float* cg121  = (const float*)d_in[15];
    const float* mix122 = (const float*)d_in[16];
    const float* cg122  = (const float*)d_in[17];
    const float* mix123 = (const float*)d_in[18];
    const float* cg123  = (const float*)d_in[19];
    const float* mix132 = (const float*)d_in[20];
    const float* cg132  = (const float*)d_in[21];
    const float* mix133 = (const float*)d_in[22];
    const float* cg133  = (const float*)d_in[23];
    const float* mix231 = (const float*)d_in[24];
    const float* cg231  = (const float*)d_in[25];
    const float* mix232 = (const float*)d_in[26];
    const float* cg232  = (const float*)d_in[27];
    const float* mix233 = (const float*)d_in[28];
    const float* cg233  = (const float*)d_in[29];

    dim3 grid(NN);
    dim3 block(FF);
    hipLaunchKernelGGL(selfmix_kernel, grid, block, 0, stream,
                       x0, x1, x2, x3,
                       keep0, keep1, keep2, keep3,
                       mix011, cg011, mix022, cg022, mix033, cg033,
                       mix121, cg121, mix122, cg122, mix123, cg123,
                       mix132, cg132, mix133, cg133,
                       mix231, cg231, mix232, cg232, mix233, cg233,
                       (float*)d_out);
}

// Round 3
// 161.669 us; speedup vs baseline: 1.1659x; 1.1236x over previous
//
#include <hip/hip_runtime.h>
#include <stdint.h>

constexpr int NN = 20000;
constexpr int FF = 256;

typedef float v2f __attribute__((ext_vector_type(2)));

// Scalar path for CG coefficients: addrspace(4) + wave-uniform address
// -> s_load -> SGPR, splat into packed operand.
typedef const __attribute__((address_space(4))) float* cgp;
#define CGP(p) ((cgp)(uintptr_t)(p))

__device__ __forceinline__ v2f ld2(const float* p) {
    return *(const v2f*)p;
}
__device__ __forceinline__ void st2(float* p, v2f v) {
    *(v2f*)p = v;
}
__device__ __forceinline__ v2f pfma(v2f a, v2f b, v2f c) {
    return __builtin_elementwise_fma(a, b, c);
}
__device__ __forceinline__ v2f splat(float s) {
    v2f r = {s, s};
    return r;
}

__global__ __launch_bounds__(128, 2) void selfmix_kernel(
    const float* __restrict__ x0, const float* __restrict__ x1,
    const float* __restrict__ x2, const float* __restrict__ x3,
    const float* __restrict__ keep0, const float* __restrict__ keep1,
    const float* __restrict__ keep2, const float* __restrict__ keep3,
    const float* __restrict__ mix011, const float* __restrict__ cg011,
    const float* __restrict__ mix022, const float* __restrict__ cg022,
    const float* __restrict__ mix033, const float* __restrict__ cg033,
    const float* __restrict__ mix121, const float* __restrict__ cg121,
    const float* __restrict__ mix122, const float* __restrict__ cg122,
    const float* __restrict__ mix123, const float* __restrict__ cg123,
    const float* __restrict__ mix132, const float* __restrict__ cg132,
    const float* __restrict__ mix133, const float* __restrict__ cg133,
    const float* __restrict__ mix231, const float* __restrict__ cg231,
    const float* __restrict__ mix232, const float* __restrict__ cg232,
    const float* __restrict__ mix233, const float* __restrict__ cg233,
    float* __restrict__ out)
{
    const int n = blockIdx.x;
    const int fp = threadIdx.x;      // feature-pair index 0..127
    const int f2 = fp * 2;           // byte-feature base

    // ---- per-feature coefficients (coalesced float2 loads) ----
    const v2f k0 = ld2(keep0 + f2), k1 = ld2(keep1 + f2);
    const v2f k2 = ld2(keep2 + f2), k3 = ld2(keep3 + f2);
    const v2f m011 = ld2(mix011 + f2), m022 = ld2(mix022 + f2), m033 = ld2(mix033 + f2);
    const v2f m121 = ld2(mix121 + f2), m122 = ld2(mix122 + f2), m123 = ld2(mix123 + f2);
    const v2f m132 = ld2(mix132 + f2), m133 = ld2(mix133 + f2);
    const v2f m231 = ld2(mix231 + f2), m232 = ld2(mix232 + f2), m233 = ld2(mix233 + f2);

    // ---- load x fragments (8 B/lane, fully coalesced) ----
    v2f a0 = ld2(x0 + n * FF + f2);
    v2f a1[3], a2[5], a3[7];
#pragma unroll
    for (int i = 0; i < 3; ++i) a1[i] = ld2(x1 + (n * 3 + i) * FF + f2);
#pragma unroll
    for (int i = 0; i < 5; ++i) a2[i] = ld2(x2 + (n * 5 + i) * FF + f2);
#pragma unroll
    for (int i = 0; i < 7; ++i) a3[i] = ld2(x3 + (n * 7 + i) * FF + f2);

    // ---- keep path ----
    v2f y0 = k0 * a0;
    v2f y1[3], y2[5], y3[7];
#pragma unroll
    for (int i = 0; i < 3; ++i) y1[i] = k1 * a1[i];
#pragma unroll
    for (int i = 0; i < 5; ++i) y2[i] = k2 * a2[i];
#pragma unroll
    for (int i = 0; i < 7; ++i) y3[i] = k3 * a3[i];

    // ---- mixing path: ij-outer, k-inner; packed FMAs, cg via SGPR splat ----

    // group (0,1) -> L=1
    {
        cgp cg = CGP(cg011);
        v2f t[3] = {};
#pragma unroll
        for (int j = 0; j < 3; ++j) {
            const v2f p = a0 * a1[j];
#pragma unroll
            for (int k = 0; k < 3; ++k) t[k] = pfma(splat(cg[j * 3 + k]), p, t[k]);
        }
#pragma unroll
        for (int k = 0; k < 3; ++k) y1[k] = pfma(m011, t[k], y1[k]);
    }

    // group (0,2) -> L=2
    {
        cgp cg = CGP(cg022);
        v2f t[5] = {};
#pragma unroll
        for (int j = 0; j < 5; ++j) {
            const v2f p = a0 * a2[j];
#pragma unroll
            for (int k = 0; k < 5; ++k) t[k] = pfma(splat(cg[j * 5 + k]), p, t[k]);
        }
#pragma unroll
        for (int k = 0; k < 5; ++k) y2[k] = pfma(m022, t[k], y2[k]);
    }

    // group (0,3) -> L=3
    {
        cgp cg = CGP(cg033);
        v2f t[7] = {};
#pragma unroll
        for (int j = 0; j < 7; ++j) {
            const v2f p = a0 * a3[j];
#pragma unroll
            for (int k = 0; k < 7; ++k) t[k] = pfma(splat(cg[j * 7 + k]), p, t[k]);
        }
#pragma unroll
        for (int k = 0; k < 7; ++k) y3[k] = pfma(m033, t[k], y3[k]);
    }

    // group (1,2) -> L=1,2,3 (shared products)
    {
        cgp c1 = CGP(cg121);
        cgp c2 = CGP(cg122);
        cgp c3 = CGP(cg123);
        v2f t1[3] = {}, t2[5] = {}, t3[7] = {};
#pragma unroll
        for (int i = 0; i < 3; ++i) {
#pragma unroll
            for (int j = 0; j < 5; ++j) {
                const int ij = i * 5 + j;
                const v2f p = a1[i] * a2[j];
#pragma unroll
                for (int k = 0; k < 3; ++k) t1[k] = pfma(splat(c1[ij * 3 + k]), p, t1[k]);
#pragma unroll
                for (int k = 0; k < 5; ++k) t2[k] = pfma(splat(c2[ij * 5 + k]), p, t2[k]);
#pragma unroll
                for (int k = 0; k < 7; ++k) t3[k] = pfma(splat(c3[ij * 7 + k]), p, t3[k]);
            }
        }
#pragma unroll
        for (int k = 0; k < 3; ++k) y1[k] = pfma(m121, t1[k], y1[k]);
#pragma unroll
        for (int k = 0; k < 5; ++k) y2[k] = pfma(m122, t2[k], y2[k]);
#pragma unroll
        for (int k = 0; k < 7; ++k) y3[k] = pfma(m123, t3[k], y3[k]);
    }

    // group (1,3) -> L=2,3 (shared products)
    {
        cgp c2 = CGP(cg132);
        cgp c3 = CGP(cg133);
        v2f t2[5] = {}, t3[7] = {};
#pragma unroll
        for (int i = 0; i < 3; ++i) {
#pragma unroll
            for (int j = 0; j < 7; ++j) {
                const int ij = i * 7 + j;
                const v2f p = a1[i] * a3[j];
#pragma unroll
                for (int k = 0; k < 5; ++k) t2[k] = pfma(splat(c2[ij * 5 + k]), p, t2[k]);
#pragma unroll
                for (int k = 0; k < 7; ++k) t3[k] = pfma(splat(c3[ij * 7 + k]), p, t3[k]);
            }
        }
#pragma unroll
        for (int k = 0; k < 5; ++k) y2[k] = pfma(m132, t2[k], y2[k]);
#pragma unroll
        for (int k = 0; k < 7; ++k) y3[k] = pfma(m133, t3[k], y3[k]);
    }

    // group (2,3) -> L=1,2,3 (shared products)
    {
        cgp c1 = CGP(cg231);
        cgp c2 = CGP(cg232);
        cgp c3 = CGP(cg233);
        v2f t1[3] = {}, t2[5] = {}, t3[7] = {};
#pragma unroll
        for (int i = 0; i < 5; ++i) {
#pragma unroll
            for (int j = 0; j < 7; ++j) {
                const int ij = i * 7 + j;
                const v2f p = a2[i] * a3[j];
#pragma unroll
                for (int k = 0; k < 3; ++k) t1[k] = pfma(splat(c1[ij * 3 + k]), p, t1[k]);
#pragma unroll
                for (int k = 0; k < 5; ++k) t2[k] = pfma(splat(c2[ij * 5 + k]), p, t2[k]);
#pragma unroll
                for (int k = 0; k < 7; ++k) t3[k] = pfma(splat(c3[ij * 7 + k]), p, t3[k]);
            }
        }
#pragma unroll
        for (int k = 0; k < 3; ++k) y1[k] = pfma(m231, t1[k], y1[k]);
#pragma unroll
        for (int k = 0; k < 5; ++k) y2[k] = pfma(m232, t2[k], y2[k]);
#pragma unroll
        for (int k = 0; k < 7; ++k) y3[k] = pfma(m233, t3[k], y3[k]);
    }

    // ---- store (concatenated outputs: y0 | y1 | y2 | y3) ----
    float* o0 = out;                          // N*1*F
    float* o1 = out + (size_t)NN * FF;        // N*3*F
    float* o2 = out + (size_t)NN * 4 * FF;    // N*5*F
    float* o3 = out + (size_t)NN * 9 * FF;    // N*7*F

    st2(o0 + n * FF + f2, y0);
#pragma unroll
    for (int k = 0; k < 3; ++k) st2(o1 + (n * 3 + k) * FF + f2, y1[k]);
#pragma unroll
    for (int k = 0; k < 5; ++k) st2(o2 + (n * 5 + k) * FF + f2, y2[k]);
#pragma unroll
    for (int k = 0; k < 7; ++k) st2(o3 + (n * 7 + k) * FF + f2, y3[k]);
}

extern "C" void kernel_launch(void* const* d_in, const int* in_sizes, int n_in,
                              void* d_out, int out_size, void* d_ws, size_t ws_size,
                              hipStream_t stream) {
    const float* x0 = (const float*)d_in[0];
    const float* x1 = (const float*)d_in[1];
    const float* x2 = (const float*)d_in[2];
    const float* x3 = (const float*)d_in[3];
    const float* keep0 = (const float*)d_in[4];
    const float* keep1 = (const float*)d_in[5];
    const float* keep2 = (const float*)d_in[6];
    const float* keep3 = (const float*)d_in[7];
    const float* mix011 = (const float*)d_in[8];
    const float* cg011  = (const float*)d_in[9];
    const float* mix022 = (const float*)d_in[10];
    const float* cg022  = (const float*)d_in[11];
    const float* mix033 = (const float*)d_in[12];
    const float* cg033  = (const float*)d_in[13];
    const float* mix121 = (const float*)d_in[14];
    const float* cg121  = (const float*)d_in[15];
    const float* mix122 = (const float*)d_in[16];
    const float* cg122  = (const float*)d_in[17];
    const float* mix123 = (const float*)d_in[18];
    const float* cg123  = (const float*)d_in[19];
    const float* mix132 = (const float*)d_in[20];
    const float* cg132  = (const float*)d_in[21];
    const float* mix133 = (const float*)d_in[22];
    const float* cg133  = (const float*)d_in[23];
    const float* mix231 = (const float*)d_in[24];
    const float* cg231  = (const float*)d_in[25];
    const float* mix232 = (const float*)d_in[26];
    const float* cg232  = (const float*)d_in[27];
    const float* mix233 = (const float*)d_in[28];
    const float* cg233  = (const float*)d_in[29];

    dim3 grid(NN);
    dim3 block(FF / 2);   // 128 threads: one node's 256 features as float2 pairs
    hipLaunchKernelGGL(selfmix_kernel, grid, block, 0, stream,
                       x0, x1, x2, x3,
                       keep0, keep1, keep2, keep3,
                       mix011, cg011, mix022, cg022, mix033, cg033,
                       mix121, cg121, mix122, cg122, mix123, cg123,
                       mix132, cg132, mix133, cg133,
                       mix231, cg231, mix232, cg232, mix233, cg233,
                       (float*)d_out);
}